// Round 8
// baseline (381.510 us; speedup 1.0000x reference)
//
#include <hip/hip_runtime.h>
#include <hip/hip_cooperative_groups.h>
#include <math.h>

namespace cg = cooperative_groups;

#define NN    65536
#define CTRLD 128
#define WLEN  1542
#define RLEN  518
#define EPSF  1e-16f
#define GRIDB 1024
#define ROWSB 64     // rows per block
#define RPWV  16     // rows per wave

typedef float vf2 __attribute__((ext_vector_type(2)));

struct KP {
  const float* mem0; const float* cont;
  unsigned* mem8;                     // fp8 global shadow (fallback path only)
  const float* kW; const float* sW; const float* eW; const float* aW;
  const float* kR; const float* sR; float* kn;
  float *dotR, *dotW, *n2v;
  float *wunW, *pSW, *wunR, *pSR;
  float *pZr, *pZw;
  float *rp, *p2, *hbuf;
  const float *W1, *b1, *W2, *b2;
  float* out;
  const float *x, *Wc, *bc, *Ww, *bw, *Wr, *br;
  float *contw, *kWw, *sWw, *eWw, *aWw, *kRw, *sRw;
};

// 1024 + 5120 + 32 + 32768 = 38944 B -> 4 blocks/CU (155.8 <= 160 KB)
struct SmemAll {
  float red[256];
  float big[1280];
  float zsh[4][2];
  unsigned m8[ROWSB*128];   // 64 rows x 512 fp8 = 32 KB, persistent across grid.sync
};

__device__ __forceinline__ float softplusf_(float x){
    return x > 0.f ? x + log1pf(expf(-x)) : log1pf(expf(x));
}
__device__ __forceinline__ float sigmoidf_(float x){ return 1.f/(1.f+expf(-x)); }
__device__ __forceinline__ float dot4_(const float4& a, const float4& b){
    return a.x*b.x + a.y*b.y + a.z*b.z + a.w*b.w;
}

__device__ __forceinline__ float blockReduce256(float v, float* red){
    int t = threadIdx.x;
    red[t] = v; __syncthreads();
    for(int s = 128; s; s >>= 1){ if(t < s) red[t] += red[t+s]; __syncthreads(); }
    float r = red[0]; __syncthreads();
    return r;
}
__device__ __forceinline__ void waveReduce3(float& a, float& b, float& c){
    for(int o = 32; o; o >>= 1){
        a += __shfl_down(a,o); b += __shfl_down(b,o); c += __shfl_down(c,o);
    }
}
__device__ __forceinline__ void waveReduce1(float& a){
    for(int o = 32; o; o >>= 1) a += __shfl_down(a,o);
}

// ---- fp8 quant/dequant (x64 pre-scale keeps data in e4m3 normal range) ----
__device__ __forceinline__ void quant8(const float4& v0, const float4& v1,
                                       unsigned& q0, unsigned& q1){
    int a = __builtin_amdgcn_cvt_pk_fp8_f32(v0.x*64.f, v0.y*64.f, 0, false);
    a     = __builtin_amdgcn_cvt_pk_fp8_f32(v0.z*64.f, v0.w*64.f, a, true);
    int b = __builtin_amdgcn_cvt_pk_fp8_f32(v1.x*64.f, v1.y*64.f, 0, false);
    b     = __builtin_amdgcn_cvt_pk_fp8_f32(v1.z*64.f, v1.w*64.f, b, true);
    q0 = (unsigned)a; q1 = (unsigned)b;
}
__device__ __forceinline__ void dequant8(unsigned q0, unsigned q1,
                                         float4& v0, float4& v1){
    vf2 a = __builtin_amdgcn_cvt_pk_f32_fp8((int)q0, false);
    vf2 b = __builtin_amdgcn_cvt_pk_f32_fp8((int)q0, true);
    vf2 c = __builtin_amdgcn_cvt_pk_f32_fp8((int)q1, false);
    vf2 d = __builtin_amdgcn_cvt_pk_f32_fp8((int)q1, true);
    const float s = 1.f/64.f;
    v0 = make_float4(a.x*s, a.y*s, b.x*s, b.y*s);
    v1 = make_float4(c.x*s, c.y*s, d.x*s, d.y*s);
}

// ================= owor phase (blocks 0..32) =================
__device__ __forceinline__ void owor_phase(const KP& p, SmemAll& sm, int bid){
    float* cs = sm.big;
    int tid = threadIdx.x;
    for(int q = tid; q < 512; q += 256){
        int t = q >> 7, c = q & 127;
        float acc = p.bc[c];
        const float* xr = p.x + t*CTRLD;
        const float* wr = p.Wc + c*CTRLD;
        for(int d = 0; d < CTRLD; ++d) acc += xr[d]*wr[d];
        cs[q] = acc;
        if(bid == 0) p.contw[q] = acc;
    }
    __syncthreads();
    int idx = bid*256 + tid;
    if(idx < 4*WLEN){
        int t = idx / WLEN, o = idx % WLEN;
        float acc = p.bw[o];
        const float* cr = cs + t*CTRLD;
        const float* wr = p.Ww + o*CTRLD;
        for(int d = 0; d < CTRLD; ++d) acc += cr[d]*wr[d];
        if(o < 512)       p.kWw[t*512 + o] = acc;
        else if(o < 518)  p.sWw[t*8 + (o-512)] = acc;
        else if(o < 1030) p.eWw[t*512 + (o-518)] = sigmoidf_(acc);
        else              p.aWw[t*512 + (o-1030)] = acc;
    } else {
        int j = idx - 4*WLEN;
        if(j < 4*RLEN){
            int t = j / RLEN, o = j % RLEN;
            float acc = p.br[o];
            const float* cr = cs + t*CTRLD;
            const float* wr = p.Wr + o*CTRLD;
            for(int d = 0; d < CTRLD; ++d) acc += cr[d]*wr[d];
            if(o < 512) p.kRw[t*512 + o] = acc;
            else        p.sRw[t*8 + (o-512)] = acc;
        }
    }
    __syncthreads();
}

// ================= sweep phase =================
// CVT: read fp32 mem0 (exact dots), quantize to fp8 (LDS if LDSM else global).
// else: dequantize fp8 base. CH chained writes -> M_{CH-1}; RP: r partials
// (RAW wunR[rstep], per-wave direct to global rp); UPD: apply write CH;
// DOTR/DOTW: dots vs kRc/kWn + exp partials + publish key norms.
template<int CH, bool RP, bool UPD, bool DOTR, bool DOTW, bool CVT, bool LDSM>
__device__ __forceinline__ void sweep_phase(const KP& p, SmemAll& sm, int rstep,
    const float* kRc, const float* sRc, int knRi,
    const float* kWn, const float* sWn, int knWi)
{
    constexpr int NW = CH + (UPD ? 1 : 0);
    constexpr int NA = (NW > 0) ? NW : 1;
    int t = threadIdx.x, bid = blockIdx.x;
    float wnorm[NA];
    #pragma unroll
    for(int j = 0; j < NW; ++j){
        float s = p.pSW[j*GRIDB+t] + p.pSW[j*GRIDB+t+256]
                + p.pSW[j*GRIDB+t+512] + p.pSW[j*GRIDB+t+768];
        wnorm[j] = 1.f/(blockReduce256(s, sm.red) + EPSF);
    }
    int wave = t >> 6, lane = t & 63;
    int c0 = 2*lane, c1 = 2*lane + 1;     // 8 contiguous floats per thread
    float4 ev0[NA], ev1[NA], av0[NA], av1[NA];
    #pragma unroll
    for(int j = 0; j < NW; ++j){
        ev0[j] = ((const float4*)(p.eW + j*512))[c0];
        ev1[j] = ((const float4*)(p.eW + j*512))[c1];
        av0[j] = ((const float4*)(p.aW + j*512))[c0];
        av1[j] = ((const float4*)(p.aW + j*512))[c1];
    }
    float4 kra, krb, kwa, kwb;
    float betaR = 0.f, betaW = 0.f, knRv = 1.f, knWv = 1.f;
    if constexpr(DOTR){
        kra = ((const float4*)kRc)[c0]; krb = ((const float4*)kRc)[c1];
        betaR = softplusf_(sRc[0]);
        float n2 = blockReduce256(dot4_(kra,kra) + dot4_(krb,krb), sm.red);
        knRv = sqrtf(n2*0.25f);           // lanes repeat 4x across waves
        if(t == 0 && bid == 0) p.kn[knRi] = knRv;
    }
    if constexpr(DOTW){
        kwa = ((const float4*)kWn)[c0]; kwb = ((const float4*)kWn)[c1];
        betaW = softplusf_(sWn[0]);
        float n2 = blockReduce256(dot4_(kwa,kwa) + dot4_(kwb,kwb), sm.red);
        knWv = sqrtf(n2*0.25f);
        if(t == 0 && bid == 0) p.kn[knWi] = knWv;
    }
    float4 rpA = {0,0,0,0}, rpB = {0,0,0,0};
    float zr = 0.f, zw = 0.f;
    int row0 = bid*ROWSB + wave*RPWV;
    for(int r = 0; r < RPWV; ++r){
        int row = row0 + r;
        int lrow = wave*RPWV + r;
        float4 v0, v1;
        if constexpr(CVT){
            const float4* src = (const float4*)p.mem0;
            v0 = src[(size_t)row*128 + c0];
            v1 = src[(size_t)row*128 + c1];
        } else {
            unsigned q0, q1;
            if constexpr(LDSM){
                q0 = sm.m8[lrow*128 + 2*lane];
                q1 = sm.m8[lrow*128 + 2*lane + 1];
            } else {
                q0 = p.mem8[(size_t)row*128 + 2*lane];
                q1 = p.mem8[(size_t)row*128 + 2*lane + 1];
            }
            dequant8(q0, q1, v0, v1);
        }
        #pragma unroll
        for(int j = 0; j < CH; ++j){
            float w = p.wunW[(size_t)j*NN + row]*wnorm[j];
            v0.x = fmaf(w, fmaf(-ev0[j].x, v0.x, av0[j].x), v0.x);
            v0.y = fmaf(w, fmaf(-ev0[j].y, v0.y, av0[j].y), v0.y);
            v0.z = fmaf(w, fmaf(-ev0[j].z, v0.z, av0[j].z), v0.z);
            v0.w = fmaf(w, fmaf(-ev0[j].w, v0.w, av0[j].w), v0.w);
            v1.x = fmaf(w, fmaf(-ev1[j].x, v1.x, av1[j].x), v1.x);
            v1.y = fmaf(w, fmaf(-ev1[j].y, v1.y, av1[j].y), v1.y);
            v1.z = fmaf(w, fmaf(-ev1[j].z, v1.z, av1[j].z), v1.z);
            v1.w = fmaf(w, fmaf(-ev1[j].w, v1.w, av1[j].w), v1.w);
        }
        if constexpr(RP){
            float wr = p.wunR[(size_t)rstep*NN + row];   // RAW; normalized at h
            rpA.x += wr*v0.x; rpA.y += wr*v0.y; rpA.z += wr*v0.z; rpA.w += wr*v0.w;
            rpB.x += wr*v1.x; rpB.y += wr*v1.y; rpB.z += wr*v1.z; rpB.w += wr*v1.w;
        }
        if constexpr(UPD){
            float w = p.wunW[(size_t)CH*NN + row]*wnorm[CH];
            v0.x = fmaf(w, fmaf(-ev0[CH].x, v0.x, av0[CH].x), v0.x);
            v0.y = fmaf(w, fmaf(-ev0[CH].y, v0.y, av0[CH].y), v0.y);
            v0.z = fmaf(w, fmaf(-ev0[CH].z, v0.z, av0[CH].z), v0.z);
            v0.w = fmaf(w, fmaf(-ev0[CH].w, v0.w, av0[CH].w), v0.w);
            v1.x = fmaf(w, fmaf(-ev1[CH].x, v1.x, av1[CH].x), v1.x);
            v1.y = fmaf(w, fmaf(-ev1[CH].y, v1.y, av1[CH].y), v1.y);
            v1.z = fmaf(w, fmaf(-ev1[CH].z, v1.z, av1[CH].z), v1.z);
            v1.w = fmaf(w, fmaf(-ev1[CH].w, v1.w, av1[CH].w), v1.w);
        }
        if constexpr(CVT){
            unsigned q0, q1;
            quant8(v0, v1, q0, q1);
            if constexpr(LDSM){
                sm.m8[lrow*128 + 2*lane]     = q0;
                sm.m8[lrow*128 + 2*lane + 1] = q1;
            } else {
                p.mem8[(size_t)row*128 + 2*lane]     = q0;
                p.mem8[(size_t)row*128 + 2*lane + 1] = q1;
            }
        }
        if constexpr(DOTR || DOTW){
            float d = 0.f, dn = 0.f;
            float n = dot4_(v0,v0) + dot4_(v1,v1);
            if constexpr(DOTR) d  = dot4_(v0,kra) + dot4_(v1,krb);
            if constexpr(DOTW) dn = dot4_(v0,kwa) + dot4_(v1,kwb);
            waveReduce3(d, dn, n);
            if(lane == 0){
                p.n2v[row] = n;
                float sn = sqrtf(n);
                if constexpr(DOTR){ p.dotR[row] = d;  zr += expf(betaR*d /(sn*knRv + EPSF)); }
                if constexpr(DOTW){ p.dotW[row] = dn; zw += expf(betaW*dn/(sn*knWv + EPSF)); }
            }
        }
    }
    if constexpr(RP){
        float* dst = p.rp + ((size_t)(bid*4 + wave))*512;   // per-wave partial
        ((float4*)dst)[c0] = rpA;
        ((float4*)dst)[c1] = rpB;
    }
    if constexpr(DOTR || DOTW){
        if(lane == 0){ sm.zsh[wave][0] = zr; sm.zsh[wave][1] = zw; }
        __syncthreads();
        if(t == 0){
            if constexpr(DOTR) p.pZr[bid] = sm.zsh[0][0]+sm.zsh[1][0]+sm.zsh[2][0]+sm.zsh[3][0];
            if constexpr(DOTW) p.pZw[bid] = sm.zsh[0][1]+sm.zsh[1][1]+sm.zsh[2][1]+sm.zsh[3][1];
        }
    }
    __syncthreads();
}

// ================= addressing-weight phase (one head) =================
__device__ __forceinline__ void whead_phase(const KP& p, SmemAll& sm,
    const float* sV, const float* dotv, const float* pZ,
    const float* wprev, const float* pSprev, int knidx,
    float* wun, float* pSout)
{
    int t = threadIdx.x, bid = blockIdx.x;
    float z = pZ[t] + pZ[t+256] + pZ[t+512] + pZ[t+768];
    float Z = blockReduce256(z, sm.red);
    float invSp = 1.f;
    if(pSprev){
        float sp = pSprev[t] + pSprev[t+256] + pSprev[t+512] + pSprev[t+768];
        invSp = 1.f/(blockReduce256(sp, sm.red) + EPSF);
    }
    float beta  = softplusf_(sV[0]);
    float g     = sigmoidf_(sV[1]);
    float s0 = sV[2], s1 = sV[3], s2 = sV[4];
    float smx = fmaxf(s0, fmaxf(s1, s2));
    float e0 = expf(s0-smx), e1 = expf(s1-smx), e2 = expf(s2-smx);
    float es = e0+e1+e2;
    s0 = e0/es; s1 = e1/es; s2 = e2/es;
    float gamma = 1.f + softplusf_(sV[5]);
    float knv = p.kn[knidx];
    float invZ = 1.f/Z;
    float wu = 0.f;
    if(t < ROWSB){
        int i = bid*ROWSB + t;
        int im = (i-1) & (NN-1), ip = (i+1) & (NN-1);
        auto wgf = [&](int j)->float{
            float a = beta*dotv[j]/(sqrtf(p.n2v[j])*knv + EPSF);
            float pv = wprev ? wprev[j]*invSp : (1.f/NN);
            return g*expf(a)*invZ + (1.f-g)*pv;
        };
        wu = powf(s0*wgf(im) + s1*wgf(i) + s2*wgf(ip), gamma);
        wun[i] = wu;
    }
    float S = blockReduce256(wu, sm.red);
    if(t == 0) pSout[bid] = S;
}

// ================= rp (4096x512 per-wave partials) -> dst (64x512) =========
__device__ __forceinline__ void rsum1_phase(const KP& p, float* dst){
    int t = threadIdx.x, b = blockIdx.x;   // caller guards b<64
    float2 acc; acc.x = 0.f; acc.y = 0.f;
    const float2* r2 = (const float2*)p.rp;
    for(int j = 0; j < 64; ++j){
        float2 v = r2[(size_t)(b*64 + j)*256 + t];
        acc.x += v.x; acc.y += v.y;
    }
    ((float2*)dst)[b*256 + t] = acc;
}

// ================= h = relu(W1 @ [cont, r]) : 8-block variant =================
__device__ __forceinline__ void h_phase(const KP& p, SmemAll& sm, int hb, int step,
                                        const float* p2src){
    int t = threadIdx.x;
    const float* pS = p.pSR + step*GRIDB;
    float sp = pS[t] + pS[t+256] + pS[t+512] + pS[t+768];
    float invS = 1.f/(blockReduce256(sp, sm.red) + EPSF);
    float2 acc; acc.x = 0.f; acc.y = 0.f;
    const float2* q = (const float2*)p2src;
    for(int j = 0; j < 64; ++j){
        float2 v = q[j*256 + t];
        acc.x += v.x; acc.y += v.y;
    }
    float* conc = sm.big;                // 640 floats
    conc[128 + 2*t]     = acc.x*invS;
    conc[128 + 2*t + 1] = acc.y*invS;
    if(t < 128) conc[t] = p.cont[step*128 + t];
    __syncthreads();
    int wave = t >> 6, lane = t & 63;
    for(int ol = wave; ol < 25; ol += 4){
        int o = hb*25 + ol;
        const float* wr = p.W1 + (size_t)o*640;
        float a = 0.f;
        for(int q2 = lane; q2 < 640; q2 += 64) a += wr[q2]*conc[q2];
        waveReduce1(a);
        if(lane == 0) p.hbuf[step*200 + o] = fmaxf(a + p.b1[o], 0.f);
    }
    __syncthreads();
}

// ================= out = W2 @ h + b2 =================
__device__ __forceinline__ void out_phase(const KP& p, int step){
    int t = threadIdx.x;
    if(t < 10){
        float a = p.b2[t];
        const float* wr = p.W2 + t*200;
        const float* h = p.hbuf + step*200;
        for(int j = 0; j < 200; ++j) a += wr[j]*h[j];
        p.out[step*10 + t] = a;
    }
}

// ================= single-block h + out (tail) =================
__device__ __forceinline__ void hfull_phase(const KP& p, SmemAll& sm, int step,
                                            const float* p2src){
    int t = threadIdx.x;
    const float* pS = p.pSR + step*GRIDB;
    float sp = pS[t] + pS[t+256] + pS[t+512] + pS[t+768];
    float invS = 1.f/(blockReduce256(sp, sm.red) + EPSF);
    float2 acc; acc.x = 0.f; acc.y = 0.f;
    const float2* q = (const float2*)p2src;
    for(int j = 0; j < 64; ++j){
        float2 v = q[j*256 + t];
        acc.x += v.x; acc.y += v.y;
    }
    float* conc = sm.big;
    conc[128 + 2*t]     = acc.x*invS;
    conc[128 + 2*t + 1] = acc.y*invS;
    if(t < 128) conc[t] = p.cont[step*128 + t];
    __syncthreads();
    int wave = t >> 6, lane = t & 63;
    float* hsh = sm.big + 640;           // 200 floats
    for(int o = wave; o < 200; o += 4){
        const float* wr = p.W1 + (size_t)o*640;
        float a = 0.f;
        for(int q2 = lane; q2 < 640; q2 += 64) a += wr[q2]*conc[q2];
        waveReduce1(a);
        if(lane == 0) hsh[o] = fmaxf(a + p.b1[o], 0.f);
    }
    __syncthreads();
    if(t < 10){
        float a = p.b2[t];
        const float* wr = p.W2 + t*200;
        for(int j = 0; j < 200; ++j) a += wr[j]*hsh[j];
        p.out[step*10 + t] = a;
    }
}

// ================= cooperative all-in-one (LDS-resident fp8 memory) =========
__global__ void __launch_bounds__(256, 4) k_coop(KP p){
    cg::grid_group g = cg::this_grid();
    __shared__ SmemAll sm;
    int bid = blockIdx.x;
    // P0: controller outputs
    if(bid < 33) owor_phase(p, sm, bid);
    g.sync();
    // A: dots kW0 + n2 on fp32 mem0; quantize slice into LDS
    sweep_phase<0,false,false,false,true,true,true>(p, sm, 0, nullptr,nullptr,0, p.kW, p.sW, 0);
    g.sync();
    // B: w_w(0)
    whead_phase(p, sm, p.sW, p.dotW, p.pZw, nullptr, nullptr, 0, p.wunW, p.pSW);
    g.sync();
    // C0: apply write0 -> M0, dots kR0 + kW1
    sweep_phase<0,false,true,true,true,false,true>(p, sm, 0, p.kR, p.sR, 1, p.kW+512, p.sW+8, 2);
    g.sync();
    // D0: w_r(0), w_w(1)
    whead_phase(p, sm, p.sR, p.dotR, p.pZr, nullptr, nullptr, 1, p.wunR, p.pSR);
    whead_phase(p, sm, p.sW+8, p.dotW, p.pZw, p.wunW, p.pSW, 2, p.wunW+NN, p.pSW+GRIDB);
    g.sync();
    // C1: chain M0, r(0) partials, write1 -> M1, dots kR1 + kW2
    sweep_phase<1,true,true,true,true,false,true>(p, sm, 0, p.kR+512, p.sR+8, 3, p.kW+1024, p.sW+16, 4);
    g.sync();
    // D1: w_r(1), w_w(2), rsum r(0)
    whead_phase(p, sm, p.sR+8, p.dotR, p.pZr, p.wunR, p.pSR, 3, p.wunR+NN, p.pSR+GRIDB);
    whead_phase(p, sm, p.sW+16, p.dotW, p.pZw, p.wunW+NN, p.pSW+GRIDB, 4,
                p.wunW+2*(size_t)NN, p.pSW+2*GRIDB);
    if(bid < 64) rsum1_phase(p, p.p2);
    g.sync();
    // C2
    sweep_phase<2,true,true,true,true,false,true>(p, sm, 1, p.kR+1024, p.sR+16, 5, p.kW+1536, p.sW+24, 6);
    g.sync();
    // D2: w_r(2), w_w(3), rsum r(1), h(0)
    whead_phase(p, sm, p.sR+16, p.dotR, p.pZr, p.wunR+NN, p.pSR+GRIDB, 5,
                p.wunR+2*(size_t)NN, p.pSR+2*GRIDB);
    whead_phase(p, sm, p.sW+24, p.dotW, p.pZw, p.wunW+2*(size_t)NN, p.pSW+2*GRIDB, 6,
                p.wunW+3*(size_t)NN, p.pSW+3*GRIDB);
    if(bid < 64) rsum1_phase(p, p.p2 + 64*512);
    if(bid >= 64 && bid < 72) h_phase(p, sm, bid-64, 0, p.p2);
    g.sync();
    // C3
    sweep_phase<3,true,true,true,false,false,true>(p, sm, 2, p.kR+1536, p.sR+24, 7, nullptr,nullptr,0);
    g.sync();
    // D3: w_r(3), rsum r(2), h(1), out(0)
    whead_phase(p, sm, p.sR+24, p.dotR, p.pZr, p.wunR+2*(size_t)NN, p.pSR+2*GRIDB, 7,
                p.wunR+3*(size_t)NN, p.pSR+3*GRIDB);
    if(bid < 64) rsum1_phase(p, p.p2);
    if(bid >= 64 && bid < 72) h_phase(p, sm, bid-64, 1, p.p2 + 64*512);
    if(bid == 72) out_phase(p, 0);
    g.sync();
    // C4: chain M3, r(3) partials
    sweep_phase<4,true,false,false,false,false,true>(p, sm, 3, nullptr,nullptr,0, nullptr,nullptr,0);
    g.sync();
    // D4: rsum r(3), h(2), out(1)
    if(bid < 64) rsum1_phase(p, p.p2 + 64*512);
    if(bid >= 64 && bid < 72) h_phase(p, sm, bid-64, 2, p.p2);
    if(bid == 72) out_phase(p, 1);
    g.sync();
    // E5: h(3)+out(3) single block; out(2)
    if(bid == 0) hfull_phase(p, sm, 3, p.p2 + 64*512);
    if(bid == 1) out_phase(p, 2);
}

// ================= fallback wrappers (fp8 shadow in GLOBAL memory) =========
__global__ void __launch_bounds__(256) g_owor(KP p){
    __shared__ SmemAll sm;
    owor_phase(p, sm, blockIdx.x);
}
__global__ void __launch_bounds__(256) g_sweepA(KP p){
    __shared__ SmemAll sm;
    sweep_phase<0,false,false,false,true,true,false>(p, sm, 0, nullptr,nullptr,0, p.kW, p.sW, 0);
}
__global__ void __launch_bounds__(256) g_sweepC0(KP p){
    __shared__ SmemAll sm;
    sweep_phase<0,false,true,true,true,false,false>(p, sm, 0, p.kR, p.sR, 1, p.kW+512, p.sW+8, 2);
}
__global__ void __launch_bounds__(256) g_sweepC1(KP p){
    __shared__ SmemAll sm;
    sweep_phase<1,true,true,true,true,false,false>(p, sm, 0, p.kR+512, p.sR+8, 3, p.kW+1024, p.sW+16, 4);
}
__global__ void __launch_bounds__(256) g_sweepC2(KP p){
    __shared__ SmemAll sm;
    sweep_phase<2,true,true,true,true,false,false>(p, sm, 1, p.kR+1024, p.sR+16, 5, p.kW+1536, p.sW+24, 6);
}
__global__ void __launch_bounds__(256) g_sweepC3(KP p){
    __shared__ SmemAll sm;
    sweep_phase<3,true,true,true,false,false,false>(p, sm, 2, p.kR+1536, p.sR+24, 7, nullptr,nullptr,0);
}
__global__ void __launch_bounds__(256) g_sweepC4(KP p){
    __shared__ SmemAll sm;
    sweep_phase<4,true,false,false,false,false,false>(p, sm, 3, nullptr,nullptr,0, nullptr,nullptr,0);
}
__global__ void __launch_bounds__(256) g_whead(KP p, const float* sV, const float* dotv,
    const float* pZ, const float* wprev, const float* pSprev, int knidx,
    float* wun, float* pSout){
    __shared__ SmemAll sm;
    whead_phase(p, sm, sV, dotv, pZ, wprev, pSprev, knidx, wun, pSout);
}
__global__ void __launch_bounds__(256) g_rsum1(KP p, float* dst){
    rsum1_phase(p, dst);
}
__global__ void __launch_bounds__(256) g_h(KP p, int step, const float* p2src){
    __shared__ SmemAll sm;
    h_phase(p, sm, blockIdx.x, step, p2src);
}
__global__ void __launch_bounds__(256) g_out(KP p, int step){
    out_phase(p, step);
}

extern "C" void kernel_launch(void* const* d_in, const int* in_sizes, int n_in,
                              void* d_out, int out_size, void* d_ws, size_t ws_size,
                              hipStream_t stream) {
    const float* x    = (const float*)d_in[0];
    const float* mem0 = (const float*)d_in[1];
    const float* Wc   = (const float*)d_in[2];
    const float* bc   = (const float*)d_in[3];
    const float* Wr   = (const float*)d_in[4];
    const float* br   = (const float*)d_in[5];
    const float* Ww   = (const float*)d_in[6];
    const float* bw   = (const float*)d_in[7];
    const float* W1   = (const float*)d_in[8];
    const float* b1   = (const float*)d_in[9];
    const float* W2   = (const float*)d_in[10];
    const float* b2   = (const float*)d_in[11];

    float* ws = (float*)d_ws;
    size_t off = 0;
    unsigned* mem8 = (unsigned*)(ws + off); off += (size_t)NN*128;  // 32 MiB fp8 shadow (fallback)
    float* wunW = ws + off; off += 4*(size_t)NN;
    float* pSW  = ws + off; off += 4*GRIDB;
    float* wunR = ws + off; off += 4*(size_t)NN;
    float* pSR  = ws + off; off += 4*GRIDB;
    float* dotR = ws + off; off += NN;
    float* dotW = ws + off; off += NN;
    float* n2v  = ws + off; off += NN;
    float* pZr  = ws + off; off += GRIDB;
    float* pZw  = ws + off; off += GRIDB;
    float* cont = ws + off; off += 512;
    float* kW   = ws + off; off += 4*512;
    float* sW   = ws + off; off += 4*8;
    float* eW   = ws + off; off += 4*512;
    float* aW   = ws + off; off += 4*512;
    float* kR   = ws + off; off += 4*512;
    float* sR   = ws + off; off += 4*8;
    float* kn   = ws + off; off += 16;
    float* rp   = ws + off; off += (size_t)4*GRIDB*512;   // per-wave partials, 8 MiB
    float* p2   = ws + off; off += 2*64*512;
    float* hbuf = ws + off; off += 1024;

    KP P;
    P.mem0 = mem0; P.cont = cont; P.mem8 = mem8;
    P.kW = kW; P.sW = sW; P.eW = eW; P.aW = aW; P.kR = kR; P.sR = sR; P.kn = kn;
    P.dotR = dotR; P.dotW = dotW; P.n2v = n2v;
    P.wunW = wunW; P.pSW = pSW; P.wunR = wunR; P.pSR = pSR;
    P.pZr = pZr; P.pZw = pZw;
    P.rp = rp; P.p2 = p2; P.hbuf = hbuf;
    P.W1 = W1; P.b1 = b1; P.W2 = W2; P.b2 = b2;
    P.out = (float*)d_out;
    P.x = x; P.Wc = Wc; P.bc = bc; P.Ww = Ww; P.bw = bw; P.Wr = Wr; P.br = br;
    P.contw = cont; P.kWw = kW; P.sWw = sW; P.eWw = eW; P.aWw = aW;
    P.kRw = kR; P.sRw = sR;

    // ---- cooperative path with safe fallback ----
    bool useCoop = false;
    int coopAttr = 0;
    if(hipDeviceGetAttribute(&coopAttr, hipDeviceAttributeCooperativeLaunch, 0) == hipSuccess
       && coopAttr){
        int nCU = 0, maxb = 0;
        if(hipDeviceGetAttribute(&nCU, hipDeviceAttributeMultiprocessorCount, 0) == hipSuccess
           && hipOccupancyMaxActiveBlocksPerMultiprocessor(&maxb, k_coop, 256, 0) == hipSuccess
           && (long)maxb*(long)nCU >= GRIDB){
            useCoop = true;
        }
    }
    if(useCoop){
        void* args[] = { (void*)&P };
        hipError_t e = hipLaunchCooperativeKernel((const void*)k_coop,
                           dim3(GRIDB), dim3(256), args, 0, stream);
        if(e != hipSuccess){ (void)hipGetLastError(); useCoop = false; }
    }
    if(!useCoop){
        g_owor  <<<33, 256, 0, stream>>>(P);
        g_sweepA<<<GRIDB, 256, 0, stream>>>(P);
        g_whead <<<GRIDB, 256, 0, stream>>>(P, sW, dotW, pZw, nullptr, nullptr, 0, wunW, pSW);
        g_sweepC0<<<GRIDB, 256, 0, stream>>>(P);
        g_whead <<<GRIDB, 256, 0, stream>>>(P, sR, dotR, pZr, nullptr, nullptr, 1, wunR, pSR);
        g_whead <<<GRIDB, 256, 0, stream>>>(P, sW+8, dotW, pZw, wunW, pSW, 2, wunW+NN, pSW+GRIDB);
        g_sweepC1<<<GRIDB, 256, 0, stream>>>(P);
        g_whead <<<GRIDB, 256, 0, stream>>>(P, sR+8, dotR, pZr, wunR, pSR, 3, wunR+NN, pSR+GRIDB);
        g_whead <<<GRIDB, 256, 0, stream>>>(P, sW+16, dotW, pZw, wunW+NN, pSW+GRIDB, 4,
                                            wunW+2*(size_t)NN, pSW+2*GRIDB);
        g_rsum1 <<<64, 256, 0, stream>>>(P, p2);
        g_sweepC2<<<GRIDB, 256, 0, stream>>>(P);
        g_whead <<<GRIDB, 256, 0, stream>>>(P, sR+16, dotR, pZr, wunR+NN, pSR+GRIDB, 5,
                                            wunR+2*(size_t)NN, pSR+2*GRIDB);
        g_whead <<<GRIDB, 256, 0, stream>>>(P, sW+24, dotW, pZw, wunW+2*(size_t)NN, pSW+2*GRIDB, 6,
                                            wunW+3*(size_t)NN, pSW+3*GRIDB);
        g_rsum1 <<<64, 256, 0, stream>>>(P, p2 + 64*512);
        g_h     <<<8, 256, 0, stream>>>(P, 0, p2);
        g_sweepC3<<<GRIDB, 256, 0, stream>>>(P);
        g_whead <<<GRIDB, 256, 0, stream>>>(P, sR+24, dotR, pZr, wunR+2*(size_t)NN, pSR+2*GRIDB, 7,
                                            wunR+3*(size_t)NN, pSR+3*GRIDB);
        g_rsum1 <<<64, 256, 0, stream>>>(P, p2);
        g_h     <<<8, 256, 0, stream>>>(P, 1, p2 + 64*512);
        g_out   <<<1, 256, 0, stream>>>(P, 0);
        g_sweepC4<<<GRIDB, 256, 0, stream>>>(P);
        g_rsum1 <<<64, 256, 0, stream>>>(P, p2 + 64*512);
        g_h     <<<8, 256, 0, stream>>>(P, 2, p2);
        g_out   <<<1, 256, 0, stream>>>(P, 1);
        g_h     <<<8, 256, 0, stream>>>(P, 3, p2 + 64*512);
        g_out   <<<1, 256, 0, stream>>>(P, 2);
        g_out   <<<1, 256, 0, stream>>>(P, 3);
    }
    (void)in_sizes; (void)n_in; (void)out_size; (void)ws_size;
}

// Round 9
// 367.107 us; speedup vs baseline: 1.0392x; 1.0392x over previous
//
#include <hip/hip_runtime.h>
#include <hip/hip_cooperative_groups.h>
#include <math.h>

namespace cg = cooperative_groups;

#define NN    65536
#define CTRLD 128
#define WLEN  1542
#define RLEN  518
#define EPSF  1e-16f
#define GRIDB 1024
#define ROWSB 64     // rows per block
#define RPWV  16     // rows per wave

typedef float vf2 __attribute__((ext_vector_type(2)));

struct KP {
  const float* mem0; const float* cont;
  unsigned* mem8;                     // fp8 shadow of the evolving memory (global, 32 MiB)
  const float* kW; const float* sW; const float* eW; const float* aW;
  const float* kR; const float* sR; float* kn;
  float *dotR, *dotW, *n2v;
  float *wunW, *pSW, *wunR, *pSR;
  float *pZr, *pZw;
  float *rp, *p2, *hbuf;
  const float *W1, *b1, *W2, *b2;
  float* out;
  const float *x, *Wc, *bc, *Ww, *bw, *Wr, *br;
  float *contw, *kWw, *sWw, *eWw, *aWw, *kRw, *sRw;
};

// 1024 + 8192 + 32 = 9248 B/block
struct SmemAll {
  float red[256];
  float big[2048];
  float zsh[4][2];
};

__device__ __forceinline__ float softplusf_(float x){
    return x > 0.f ? x + log1pf(expf(-x)) : log1pf(expf(x));
}
__device__ __forceinline__ float sigmoidf_(float x){ return 1.f/(1.f+expf(-x)); }
__device__ __forceinline__ float dot4_(const float4& a, const float4& b){
    return a.x*b.x + a.y*b.y + a.z*b.z + a.w*b.w;
}

__device__ __forceinline__ float blockReduce256(float v, float* red){
    int t = threadIdx.x;
    red[t] = v; __syncthreads();
    for(int s = 128; s; s >>= 1){ if(t < s) red[t] += red[t+s]; __syncthreads(); }
    float r = red[0]; __syncthreads();
    return r;
}
__device__ __forceinline__ void waveReduce3(float& a, float& b, float& c){
    for(int o = 32; o; o >>= 1){
        a += __shfl_down(a,o); b += __shfl_down(b,o); c += __shfl_down(c,o);
    }
}
__device__ __forceinline__ void waveReduce1(float& a){
    for(int o = 32; o; o >>= 1) a += __shfl_down(a,o);
}

// ---- fp8 quant/dequant (x64 pre-scale keeps data in e4m3 normal range) ----
__device__ __forceinline__ void quant8(const float4& v0, const float4& v1,
                                       unsigned& q0, unsigned& q1){
    int a = __builtin_amdgcn_cvt_pk_fp8_f32(v0.x*64.f, v0.y*64.f, 0, false);
    a     = __builtin_amdgcn_cvt_pk_fp8_f32(v0.z*64.f, v0.w*64.f, a, true);
    int b = __builtin_amdgcn_cvt_pk_fp8_f32(v1.x*64.f, v1.y*64.f, 0, false);
    b     = __builtin_amdgcn_cvt_pk_fp8_f32(v1.z*64.f, v1.w*64.f, b, true);
    q0 = (unsigned)a; q1 = (unsigned)b;
}
__device__ __forceinline__ void dequant8(unsigned q0, unsigned q1,
                                         float4& v0, float4& v1){
    vf2 a = __builtin_amdgcn_cvt_pk_f32_fp8((int)q0, false);
    vf2 b = __builtin_amdgcn_cvt_pk_f32_fp8((int)q0, true);
    vf2 c = __builtin_amdgcn_cvt_pk_f32_fp8((int)q1, false);
    vf2 d = __builtin_amdgcn_cvt_pk_f32_fp8((int)q1, true);
    const float s = 1.f/64.f;
    v0 = make_float4(a.x*s, a.y*s, b.x*s, b.y*s);
    v1 = make_float4(c.x*s, c.y*s, d.x*s, d.y*s);
}

// ================= owor phase (blocks 0..32) =================
__device__ __forceinline__ void owor_phase(const KP& p, SmemAll& sm, int bid){
    float* cs = sm.big;
    int tid = threadIdx.x;
    for(int q = tid; q < 512; q += 256){
        int t = q >> 7, c = q & 127;
        float acc = p.bc[c];
        const float* xr = p.x + t*CTRLD;
        const float* wr = p.Wc + c*CTRLD;
        for(int d = 0; d < CTRLD; ++d) acc += xr[d]*wr[d];
        cs[q] = acc;
        if(bid == 0) p.contw[q] = acc;
    }
    __syncthreads();
    int idx = bid*256 + tid;
    if(idx < 4*WLEN){
        int t = idx / WLEN, o = idx % WLEN;
        float acc = p.bw[o];
        const float* cr = cs + t*CTRLD;
        const float* wr = p.Ww + o*CTRLD;
        for(int d = 0; d < CTRLD; ++d) acc += cr[d]*wr[d];
        if(o < 512)       p.kWw[t*512 + o] = acc;
        else if(o < 518)  p.sWw[t*8 + (o-512)] = acc;
        else if(o < 1030) p.eWw[t*512 + (o-518)] = sigmoidf_(acc);
        else              p.aWw[t*512 + (o-1030)] = acc;
    } else {
        int j = idx - 4*WLEN;
        if(j < 4*RLEN){
            int t = j / RLEN, o = j % RLEN;
            float acc = p.br[o];
            const float* cr = cs + t*CTRLD;
            const float* wr = p.Wr + o*CTRLD;
            for(int d = 0; d < CTRLD; ++d) acc += cr[d]*wr[d];
            if(o < 512) p.kRw[t*512 + o] = acc;
            else        p.sRw[t*8 + (o-512)] = acc;
        }
    }
    __syncthreads();
}

// ================= sweep phase =================
// CVT: read fp32 mem0 (exact dots), quantize to fp8 global shadow.
// else: dequantize fp8 shadow. CH chained writes -> M_{CH-1}; RP: r partials
// (RAW wunR[rstep], LDS cross-wave reduce, block-level rp write); UPD: apply
// write CH; DOTR/DOTW: dots vs kRc/kWn + exp partials + publish key norms.
template<int CH, bool RP, bool UPD, bool DOTR, bool DOTW, bool CVT>
__device__ __forceinline__ void sweep_phase(const KP& p, SmemAll& sm, int rstep,
    const float* kRc, const float* sRc, int knRi,
    const float* kWn, const float* sWn, int knWi)
{
    constexpr int NW = CH + (UPD ? 1 : 0);
    constexpr int NA = (NW > 0) ? NW : 1;
    int t = threadIdx.x, bid = blockIdx.x;
    float wnorm[NA];
    #pragma unroll
    for(int j = 0; j < NW; ++j){
        float s = p.pSW[j*GRIDB+t] + p.pSW[j*GRIDB+t+256]
                + p.pSW[j*GRIDB+t+512] + p.pSW[j*GRIDB+t+768];
        wnorm[j] = 1.f/(blockReduce256(s, sm.red) + EPSF);
    }
    int wave = t >> 6, lane = t & 63;
    int c0 = 2*lane, c1 = 2*lane + 1;     // 8 contiguous floats per thread
    float4 ev0[NA], ev1[NA], av0[NA], av1[NA];
    #pragma unroll
    for(int j = 0; j < NW; ++j){
        ev0[j] = ((const float4*)(p.eW + j*512))[c0];
        ev1[j] = ((const float4*)(p.eW + j*512))[c1];
        av0[j] = ((const float4*)(p.aW + j*512))[c0];
        av1[j] = ((const float4*)(p.aW + j*512))[c1];
    }
    float4 kra, krb, kwa, kwb;
    float betaR = 0.f, betaW = 0.f, knRv = 1.f, knWv = 1.f;
    if constexpr(DOTR){
        kra = ((const float4*)kRc)[c0]; krb = ((const float4*)kRc)[c1];
        betaR = softplusf_(sRc[0]);
        float n2 = blockReduce256(dot4_(kra,kra) + dot4_(krb,krb), sm.red);
        knRv = sqrtf(n2*0.25f);           // lanes repeat 4x across waves
        if(t == 0 && bid == 0) p.kn[knRi] = knRv;
    }
    if constexpr(DOTW){
        kwa = ((const float4*)kWn)[c0]; kwb = ((const float4*)kWn)[c1];
        betaW = softplusf_(sWn[0]);
        float n2 = blockReduce256(dot4_(kwa,kwa) + dot4_(kwb,kwb), sm.red);
        knWv = sqrtf(n2*0.25f);
        if(t == 0 && bid == 0) p.kn[knWi] = knWv;
    }
    float4 rpA = {0,0,0,0}, rpB = {0,0,0,0};
    float zr = 0.f, zw = 0.f;
    int row0 = bid*ROWSB + wave*RPWV;
    for(int r = 0; r < RPWV; ++r){
        int row = row0 + r;
        float4 v0, v1;
        if constexpr(CVT){
            const float4* src = (const float4*)p.mem0;
            v0 = src[(size_t)row*128 + c0];
            v1 = src[(size_t)row*128 + c1];
        } else {
            unsigned q0 = p.mem8[(size_t)row*128 + 2*lane];
            unsigned q1 = p.mem8[(size_t)row*128 + 2*lane + 1];
            dequant8(q0, q1, v0, v1);
        }
        #pragma unroll
        for(int j = 0; j < CH; ++j){
            float w = p.wunW[(size_t)j*NN + row]*wnorm[j];
            v0.x = fmaf(w, fmaf(-ev0[j].x, v0.x, av0[j].x), v0.x);
            v0.y = fmaf(w, fmaf(-ev0[j].y, v0.y, av0[j].y), v0.y);
            v0.z = fmaf(w, fmaf(-ev0[j].z, v0.z, av0[j].z), v0.z);
            v0.w = fmaf(w, fmaf(-ev0[j].w, v0.w, av0[j].w), v0.w);
            v1.x = fmaf(w, fmaf(-ev1[j].x, v1.x, av1[j].x), v1.x);
            v1.y = fmaf(w, fmaf(-ev1[j].y, v1.y, av1[j].y), v1.y);
            v1.z = fmaf(w, fmaf(-ev1[j].z, v1.z, av1[j].z), v1.z);
            v1.w = fmaf(w, fmaf(-ev1[j].w, v1.w, av1[j].w), v1.w);
        }
        if constexpr(RP){
            float wr = p.wunR[(size_t)rstep*NN + row];   // RAW; normalized at h
            rpA.x += wr*v0.x; rpA.y += wr*v0.y; rpA.z += wr*v0.z; rpA.w += wr*v0.w;
            rpB.x += wr*v1.x; rpB.y += wr*v1.y; rpB.z += wr*v1.z; rpB.w += wr*v1.w;
        }
        if constexpr(UPD){
            float w = p.wunW[(size_t)CH*NN + row]*wnorm[CH];
            v0.x = fmaf(w, fmaf(-ev0[CH].x, v0.x, av0[CH].x), v0.x);
            v0.y = fmaf(w, fmaf(-ev0[CH].y, v0.y, av0[CH].y), v0.y);
            v0.z = fmaf(w, fmaf(-ev0[CH].z, v0.z, av0[CH].z), v0.z);
            v0.w = fmaf(w, fmaf(-ev0[CH].w, v0.w, av0[CH].w), v0.w);
            v1.x = fmaf(w, fmaf(-ev1[CH].x, v1.x, av1[CH].x), v1.x);
            v1.y = fmaf(w, fmaf(-ev1[CH].y, v1.y, av1[CH].y), v1.y);
            v1.z = fmaf(w, fmaf(-ev1[CH].z, v1.z, av1[CH].z), v1.z);
            v1.w = fmaf(w, fmaf(-ev1[CH].w, v1.w, av1[CH].w), v1.w);
        }
        if constexpr(CVT){
            unsigned q0, q1;
            quant8(v0, v1, q0, q1);
            p.mem8[(size_t)row*128 + 2*lane]     = q0;
            p.mem8[(size_t)row*128 + 2*lane + 1] = q1;
        }
        if constexpr(DOTR || DOTW){
            float d = 0.f, dn = 0.f;
            float n = dot4_(v0,v0) + dot4_(v1,v1);
            if constexpr(DOTR) d  = dot4_(v0,kra) + dot4_(v1,krb);
            if constexpr(DOTW) dn = dot4_(v0,kwa) + dot4_(v1,kwb);
            waveReduce3(d, dn, n);
            if(lane == 0){
                p.n2v[row] = n;
                float sn = sqrtf(n);
                if constexpr(DOTR){ p.dotR[row] = d;  zr += expf(betaR*d /(sn*knRv + EPSF)); }
                if constexpr(DOTW){ p.dotW[row] = dn; zw += expf(betaW*dn/(sn*knWv + EPSF)); }
            }
        }
    }
    if constexpr(DOTR || DOTW){
        if(lane == 0){ sm.zsh[wave][0] = zr; sm.zsh[wave][1] = zw; }
    }
    if constexpr(RP){
        ((float4*)(sm.big + wave*512))[c0] = rpA;
        ((float4*)(sm.big + wave*512))[c1] = rpB;
    }
    __syncthreads();
    if constexpr(RP){
        p.rp[(size_t)bid*512 + t] =
            sm.big[t] + sm.big[512+t] + sm.big[1024+t] + sm.big[1536+t];
        p.rp[(size_t)bid*512 + t + 256] =
            sm.big[t+256] + sm.big[768+t] + sm.big[1280+t] + sm.big[1792+t];
    }
    if(t == 0){
        if constexpr(DOTR) p.pZr[bid] = sm.zsh[0][0]+sm.zsh[1][0]+sm.zsh[2][0]+sm.zsh[3][0];
        if constexpr(DOTW) p.pZw[bid] = sm.zsh[0][1]+sm.zsh[1][1]+sm.zsh[2][1]+sm.zsh[3][1];
    }
    __syncthreads();
}

// ================= addressing-weight phase (one head) =================
__device__ __forceinline__ void whead_phase(const KP& p, SmemAll& sm,
    const float* sV, const float* dotv, const float* pZ,
    const float* wprev, const float* pSprev, int knidx,
    float* wun, float* pSout)
{
    int t = threadIdx.x, bid = blockIdx.x;
    float z = pZ[t] + pZ[t+256] + pZ[t+512] + pZ[t+768];
    float Z = blockReduce256(z, sm.red);
    float invSp = 1.f;
    if(pSprev){
        float sp = pSprev[t] + pSprev[t+256] + pSprev[t+512] + pSprev[t+768];
        invSp = 1.f/(blockReduce256(sp, sm.red) + EPSF);
    }
    float beta  = softplusf_(sV[0]);
    float g     = sigmoidf_(sV[1]);
    float s0 = sV[2], s1 = sV[3], s2 = sV[4];
    float smx = fmaxf(s0, fmaxf(s1, s2));
    float e0 = expf(s0-smx), e1 = expf(s1-smx), e2 = expf(s2-smx);
    float es = e0+e1+e2;
    s0 = e0/es; s1 = e1/es; s2 = e2/es;
    float gamma = 1.f + softplusf_(sV[5]);
    float knv = p.kn[knidx];
    float invZ = 1.f/Z;
    float wu = 0.f;
    if(t < ROWSB){
        int i = bid*ROWSB + t;
        int im = (i-1) & (NN-1), ip = (i+1) & (NN-1);
        auto wgf = [&](int j)->float{
            float a = beta*dotv[j]/(sqrtf(p.n2v[j])*knv + EPSF);
            float pv = wprev ? wprev[j]*invSp : (1.f/NN);
            return g*expf(a)*invZ + (1.f-g)*pv;
        };
        wu = powf(s0*wgf(im) + s1*wgf(i) + s2*wgf(ip), gamma);
        wun[i] = wu;
    }
    float S = blockReduce256(wu, sm.red);
    if(t == 0) pSout[bid] = S;
}

// ================= rp (1024x512) -> dst (64x512) =================
__device__ __forceinline__ void rsum1_phase(const KP& p, float* dst){
    int t = threadIdx.x, b = blockIdx.x;   // caller guards b<64
    float2 acc; acc.x = 0.f; acc.y = 0.f;
    const float2* r2 = (const float2*)p.rp;
    for(int j = 0; j < 16; ++j){
        float2 v = r2[(size_t)(b*16 + j)*256 + t];
        acc.x += v.x; acc.y += v.y;
    }
    ((float2*)dst)[b*256 + t] = acc;
}

// ================= h = relu(W1 @ [cont, r]) : 8-block variant =================
__device__ __forceinline__ void h_phase(const KP& p, SmemAll& sm, int hb, int step,
                                        const float* p2src){
    int t = threadIdx.x;
    const float* pS = p.pSR + step*GRIDB;
    float sp = pS[t] + pS[t+256] + pS[t+512] + pS[t+768];
    float invS = 1.f/(blockReduce256(sp, sm.red) + EPSF);
    float2 acc; acc.x = 0.f; acc.y = 0.f;
    const float2* q = (const float2*)p2src;
    for(int j = 0; j < 64; ++j){
        float2 v = q[j*256 + t];
        acc.x += v.x; acc.y += v.y;
    }
    float* conc = sm.big;                // 640 floats
    conc[128 + 2*t]     = acc.x*invS;
    conc[128 + 2*t + 1] = acc.y*invS;
    if(t < 128) conc[t] = p.cont[step*128 + t];
    __syncthreads();
    int wave = t >> 6, lane = t & 63;
    for(int ol = wave; ol < 25; ol += 4){
        int o = hb*25 + ol;
        const float* wr = p.W1 + (size_t)o*640;
        float a = 0.f;
        for(int q2 = lane; q2 < 640; q2 += 64) a += wr[q2]*conc[q2];
        waveReduce1(a);
        if(lane == 0) p.hbuf[step*200 + o] = fmaxf(a + p.b1[o], 0.f);
    }
    __syncthreads();
}

// ================= out = W2 @ h + b2 =================
__device__ __forceinline__ void out_phase(const KP& p, int step){
    int t = threadIdx.x;
    if(t < 10){
        float a = p.b2[t];
        const float* wr = p.W2 + t*200;
        const float* h = p.hbuf + step*200;
        for(int j = 0; j < 200; ++j) a += wr[j]*h[j];
        p.out[step*10 + t] = a;
    }
}

// ================= single-block h + out (tail) =================
__device__ __forceinline__ void hfull_phase(const KP& p, SmemAll& sm, int step,
                                            const float* p2src){
    int t = threadIdx.x;
    const float* pS = p.pSR + step*GRIDB;
    float sp = pS[t] + pS[t+256] + pS[t+512] + pS[t+768];
    float invS = 1.f/(blockReduce256(sp, sm.red) + EPSF);
    float2 acc; acc.x = 0.f; acc.y = 0.f;
    const float2* q = (const float2*)p2src;
    for(int j = 0; j < 64; ++j){
        float2 v = q[j*256 + t];
        acc.x += v.x; acc.y += v.y;
    }
    float* conc = sm.big;
    conc[128 + 2*t]     = acc.x*invS;
    conc[128 + 2*t + 1] = acc.y*invS;
    if(t < 128) conc[t] = p.cont[step*128 + t];
    __syncthreads();
    int wave = t >> 6, lane = t & 63;
    float* hsh = sm.big + 640;           // 200 floats
    for(int o = wave; o < 200; o += 4){
        const float* wr = p.W1 + (size_t)o*640;
        float a = 0.f;
        for(int q2 = lane; q2 < 640; q2 += 64) a += wr[q2]*conc[q2];
        waveReduce1(a);
        if(lane == 0) hsh[o] = fmaxf(a + p.b1[o], 0.f);
    }
    __syncthreads();
    if(t < 10){
        float a = p.b2[t];
        const float* wr = p.W2 + t*200;
        for(int j = 0; j < 200; ++j) a += wr[j]*hsh[j];
        p.out[step*10 + t] = a;
    }
}

// ================= cooperative all-in-one (fp8 global shadow) =========
__global__ void __launch_bounds__(256, 4) k_coop(KP p){
    cg::grid_group g = cg::this_grid();
    __shared__ SmemAll sm;
    int bid = blockIdx.x;
    // P0: controller outputs
    if(bid < 33) owor_phase(p, sm, bid);
    g.sync();
    // A: dots kW0 + n2 on fp32 mem0; write fp8 shadow
    sweep_phase<0,false,false,false,true,true>(p, sm, 0, nullptr,nullptr,0, p.kW, p.sW, 0);
    g.sync();
    // B: w_w(0)
    whead_phase(p, sm, p.sW, p.dotW, p.pZw, nullptr, nullptr, 0, p.wunW, p.pSW);
    g.sync();
    // C0: apply write0 -> M0, dots kR0 + kW1
    sweep_phase<0,false,true,true,true,false>(p, sm, 0, p.kR, p.sR, 1, p.kW+512, p.sW+8, 2);
    g.sync();
    // D0: w_r(0), w_w(1)
    whead_phase(p, sm, p.sR, p.dotR, p.pZr, nullptr, nullptr, 1, p.wunR, p.pSR);
    whead_phase(p, sm, p.sW+8, p.dotW, p.pZw, p.wunW, p.pSW, 2, p.wunW+NN, p.pSW+GRIDB);
    g.sync();
    // C1: chain M0, r(0) partials, write1 -> M1, dots kR1 + kW2
    sweep_phase<1,true,true,true,true,false>(p, sm, 0, p.kR+512, p.sR+8, 3, p.kW+1024, p.sW+16, 4);
    g.sync();
    // D1: w_r(1), w_w(2), rsum r(0)
    whead_phase(p, sm, p.sR+8, p.dotR, p.pZr, p.wunR, p.pSR, 3, p.wunR+NN, p.pSR+GRIDB);
    whead_phase(p, sm, p.sW+16, p.dotW, p.pZw, p.wunW+NN, p.pSW+GRIDB, 4,
                p.wunW+2*(size_t)NN, p.pSW+2*GRIDB);
    if(bid < 64) rsum1_phase(p, p.p2);
    g.sync();
    // C2
    sweep_phase<2,true,true,true,true,false>(p, sm, 1, p.kR+1024, p.sR+16, 5, p.kW+1536, p.sW+24, 6);
    g.sync();
    // D2: w_r(2), w_w(3), rsum r(1), h(0)
    whead_phase(p, sm, p.sR+16, p.dotR, p.pZr, p.wunR+NN, p.pSR+GRIDB, 5,
                p.wunR+2*(size_t)NN, p.pSR+2*GRIDB);
    whead_phase(p, sm, p.sW+24, p.dotW, p.pZw, p.wunW+2*(size_t)NN, p.pSW+2*GRIDB, 6,
                p.wunW+3*(size_t)NN, p.pSW+3*GRIDB);
    if(bid < 64) rsum1_phase(p, p.p2 + 64*512);
    if(bid >= 64 && bid < 72) h_phase(p, sm, bid-64, 0, p.p2);
    g.sync();
    // C3
    sweep_phase<3,true,true,true,false,false>(p, sm, 2, p.kR+1536, p.sR+24, 7, nullptr,nullptr,0);
    g.sync();
    // D3: w_r(3), rsum r(2), h(1), out(0)
    whead_phase(p, sm, p.sR+24, p.dotR, p.pZr, p.wunR+2*(size_t)NN, p.pSR+2*GRIDB, 7,
                p.wunR+3*(size_t)NN, p.pSR+3*GRIDB);
    if(bid < 64) rsum1_phase(p, p.p2);
    if(bid >= 64 && bid < 72) h_phase(p, sm, bid-64, 1, p.p2 + 64*512);
    if(bid == 72) out_phase(p, 0);
    g.sync();
    // C4: chain M3, r(3) partials
    sweep_phase<4,true,false,false,false,false>(p, sm, 3, nullptr,nullptr,0, nullptr,nullptr,0);
    g.sync();
    // D4: rsum r(3), h(2), out(1)
    if(bid < 64) rsum1_phase(p, p.p2 + 64*512);
    if(bid >= 64 && bid < 72) h_phase(p, sm, bid-64, 2, p.p2);
    if(bid == 72) out_phase(p, 1);
    g.sync();
    // E5: h(3)+out(3) single block; out(2)
    if(bid == 0) hfull_phase(p, sm, 3, p.p2 + 64*512);
    if(bid == 1) out_phase(p, 2);
}

// ================= fallback wrappers (same math, separate launches) ========
__global__ void __launch_bounds__(256) g_owor(KP p){
    __shared__ SmemAll sm;
    owor_phase(p, sm, blockIdx.x);
}
__global__ void __launch_bounds__(256) g_sweepA(KP p){
    __shared__ SmemAll sm;
    sweep_phase<0,false,false,false,true,true>(p, sm, 0, nullptr,nullptr,0, p.kW, p.sW, 0);
}
__global__ void __launch_bounds__(256) g_sweepC0(KP p){
    __shared__ SmemAll sm;
    sweep_phase<0,false,true,true,true,false>(p, sm, 0, p.kR, p.sR, 1, p.kW+512, p.sW+8, 2);
}
__global__ void __launch_bounds__(256) g_sweepC1(KP p){
    __shared__ SmemAll sm;
    sweep_phase<1,true,true,true,true,false>(p, sm, 0, p.kR+512, p.sR+8, 3, p.kW+1024, p.sW+16, 4);
}
__global__ void __launch_bounds__(256) g_sweepC2(KP p){
    __shared__ SmemAll sm;
    sweep_phase<2,true,true,true,true,false>(p, sm, 1, p.kR+1024, p.sR+16, 5, p.kW+1536, p.sW+24, 6);
}
__global__ void __launch_bounds__(256) g_sweepC3(KP p){
    __shared__ SmemAll sm;
    sweep_phase<3,true,true,true,false,false>(p, sm, 2, p.kR+1536, p.sR+24, 7, nullptr,nullptr,0);
}
__global__ void __launch_bounds__(256) g_sweepC4(KP p){
    __shared__ SmemAll sm;
    sweep_phase<4,true,false,false,false,false>(p, sm, 3, nullptr,nullptr,0, nullptr,nullptr,0);
}
__global__ void __launch_bounds__(256) g_whead(KP p, const float* sV, const float* dotv,
    const float* pZ, const float* wprev, const float* pSprev, int knidx,
    float* wun, float* pSout){
    __shared__ SmemAll sm;
    whead_phase(p, sm, sV, dotv, pZ, wprev, pSprev, knidx, wun, pSout);
}
__global__ void __launch_bounds__(256) g_rsum1(KP p, float* dst){
    rsum1_phase(p, dst);
}
__global__ void __launch_bounds__(256) g_h(KP p, int step, const float* p2src){
    __shared__ SmemAll sm;
    h_phase(p, sm, blockIdx.x, step, p2src);
}
__global__ void __launch_bounds__(256) g_out(KP p, int step){
    out_phase(p, step);
}

extern "C" void kernel_launch(void* const* d_in, const int* in_sizes, int n_in,
                              void* d_out, int out_size, void* d_ws, size_t ws_size,
                              hipStream_t stream) {
    const float* x    = (const float*)d_in[0];
    const float* mem0 = (const float*)d_in[1];
    const float* Wc   = (const float*)d_in[2];
    const float* bc   = (const float*)d_in[3];
    const float* Wr   = (const float*)d_in[4];
    const float* br   = (const float*)d_in[5];
    const float* Ww   = (const float*)d_in[6];
    const float* bw   = (const float*)d_in[7];
    const float* W1   = (const float*)d_in[8];
    const float* b1   = (const float*)d_in[9];
    const float* W2   = (const float*)d_in[10];
    const float* b2   = (const float*)d_in[11];

    float* ws = (float*)d_ws;
    size_t off = 0;
    unsigned* mem8 = (unsigned*)(ws + off); off += (size_t)NN*128;  // 32 MiB fp8 shadow
    float* wunW = ws + off; off += 4*(size_t)NN;
    float* pSW  = ws + off; off += 4*GRIDB;
    float* wunR = ws + off; off += 4*(size_t)NN;
    float* pSR  = ws + off; off += 4*GRIDB;
    float* dotR = ws + off; off += NN;
    float* dotW = ws + off; off += NN;
    float* n2v  = ws + off; off += NN;
    float* pZr  = ws + off; off += GRIDB;
    float* pZw  = ws + off; off += GRIDB;
    float* cont = ws + off; off += 512;
    float* kW   = ws + off; off += 4*512;
    float* sW   = ws + off; off += 4*8;
    float* eW   = ws + off; off += 4*512;
    float* aW   = ws + off; off += 4*512;
    float* kR   = ws + off; off += 4*512;
    float* sR   = ws + off; off += 4*8;
    float* kn   = ws + off; off += 16;
    float* rp   = ws + off; off += (size_t)GRIDB*512;   // 2 MiB
    float* p2   = ws + off; off += 2*64*512;
    float* hbuf = ws + off; off += 1024;

    KP P;
    P.mem0 = mem0; P.cont = cont; P.mem8 = mem8;
    P.kW = kW; P.sW = sW; P.eW = eW; P.aW = aW; P.kR = kR; P.sR = sR; P.kn = kn;
    P.dotR = dotR; P.dotW = dotW; P.n2v = n2v;
    P.wunW = wunW; P.pSW = pSW; P.wunR = wunR; P.pSR = pSR;
    P.pZr = pZr; P.pZw = pZw;
    P.rp = rp; P.p2 = p2; P.hbuf = hbuf;
    P.W1 = W1; P.b1 = b1; P.W2 = W2; P.b2 = b2;
    P.out = (float*)d_out;
    P.x = x; P.Wc = Wc; P.bc = bc; P.Ww = Ww; P.bw = bw; P.Wr = Wr; P.br = br;
    P.contw = cont; P.kWw = kW; P.sWw = sW; P.eWw = eW; P.aWw = aW;
    P.kRw = kR; P.sRw = sR;

    // ---- cooperative path with safe fallback ----
    bool useCoop = false;
    int coopAttr = 0;
    if(hipDeviceGetAttribute(&coopAttr, hipDeviceAttributeCooperativeLaunch, 0) == hipSuccess
       && coopAttr){
        int nCU = 0, maxb = 0;
        if(hipDeviceGetAttribute(&nCU, hipDeviceAttributeMultiprocessorCount, 0) == hipSuccess
           && hipOccupancyMaxActiveBlocksPerMultiprocessor(&maxb, k_coop, 256, 0) == hipSuccess
           && (long)maxb*(long)nCU >= GRIDB){
            useCoop = true;
        }
    }
    if(useCoop){
        void* args[] = { (void*)&P };
        hipError_t e = hipLaunchCooperativeKernel((const void*)k_coop,
                           dim3(GRIDB), dim3(256), args, 0, stream);
        if(e != hipSuccess){ (void)hipGetLastError(); useCoop = false; }
    }
    if(!useCoop){
        g_owor  <<<33, 256, 0, stream>>>(P);
        g_sweepA<<<GRIDB, 256, 0, stream>>>(P);
        g_whead <<<GRIDB, 256, 0, stream>>>(P, sW, dotW, pZw, nullptr, nullptr, 0, wunW, pSW);
        g_sweepC0<<<GRIDB, 256, 0, stream>>>(P);
        g_whead <<<GRIDB, 256, 0, stream>>>(P, sR, dotR, pZr, nullptr, nullptr, 1, wunR, pSR);
        g_whead <<<GRIDB, 256, 0, stream>>>(P, sW+8, dotW, pZw, wunW, pSW, 2, wunW+NN, pSW+GRIDB);
        g_sweepC1<<<GRIDB, 256, 0, stream>>>(P);
        g_whead <<<GRIDB, 256, 0, stream>>>(P, sR+8, dotR, pZr, wunR, pSR, 3, wunR+NN, pSR+GRIDB);
        g_whead <<<GRIDB, 256, 0, stream>>>(P, sW+16, dotW, pZw, wunW+NN, pSW+GRIDB, 4,
                                            wunW+2*(size_t)NN, pSW+2*GRIDB);
        g_rsum1 <<<64, 256, 0, stream>>>(P, p2);
        g_sweepC2<<<GRIDB, 256, 0, stream>>>(P);
        g_whead <<<GRIDB, 256, 0, stream>>>(P, sR+16, dotR, pZr, wunR+NN, pSR+GRIDB, 5,
                                            wunR+2*(size_t)NN, pSR+2*GRIDB);
        g_whead <<<GRIDB, 256, 0, stream>>>(P, sW+24, dotW, pZw, wunW+2*(size_t)NN, pSW+2*GRIDB, 6,
                                            wunW+3*(size_t)NN, pSW+3*GRIDB);
        g_rsum1 <<<64, 256, 0, stream>>>(P, p2 + 64*512);
        g_h     <<<8, 256, 0, stream>>>(P, 0, p2);
        g_sweepC3<<<GRIDB, 256, 0, stream>>>(P);
        g_whead <<<GRIDB, 256, 0, stream>>>(P, sR+24, dotR, pZr, wunR+2*(size_t)NN, pSR+2*GRIDB, 7,
                                            wunR+3*(size_t)NN, pSR+3*GRIDB);
        g_rsum1 <<<64, 256, 0, stream>>>(P, p2);
        g_h     <<<8, 256, 0, stream>>>(P, 1, p2 + 64*512);
        g_out   <<<1, 256, 0, stream>>>(P, 0);
        g_sweepC4<<<GRIDB, 256, 0, stream>>>(P);
        g_rsum1 <<<64, 256, 0, stream>>>(P, p2 + 64*512);
        g_h     <<<8, 256, 0, stream>>>(P, 2, p2);
        g_out   <<<1, 256, 0, stream>>>(P, 1);
        g_h     <<<8, 256, 0, stream>>>(P, 3, p2 + 64*512);
        g_out   <<<1, 256, 0, stream>>>(P, 2);
        g_out   <<<1, 256, 0, stream>>>(P, 3);
    }
    (void)in_sizes; (void)n_in; (void)out_size; (void)ws_size;
}